// Round 7
// baseline (410.126 us; speedup 1.0000x reference)
//
#include <hip/hip_runtime.h>
#include <stdint.h>

#define N_ROWS 8192
#define IN_F   1024
#define OUT_F  1024
#define NG     5
#define KTOT   (IN_F * NG)  // 5120, k = g*1024 + i (g-major)

typedef float          f32x4 __attribute__((ext_vector_type(4)));
typedef short          s16x8 __attribute__((ext_vector_type(8)));
typedef unsigned short u16x8 __attribute__((ext_vector_type(8)));

__device__ __forceinline__ unsigned short f2bf_rne(float f) {
    unsigned u = __float_as_uint(f);
    u = (u + 0x7fffu + ((u >> 16) & 1u)) >> 16;
    return (unsigned short)u;
}
__device__ __forceinline__ float bf2f(unsigned short h) {
    return __uint_as_float(((unsigned)h) << 16);
}

// ---------- prep 1: P[n][i] = u16 encode of tanh(x[n][i]) ----------
// u = rint((tanh+1)*32767); decode xc = u/32767-1 (max err 1.5e-5). P = 16 MiB
// -> L3-resident for the GEMM (this is why inline-transform beats A-planes:
// R6 measured the 160MB A-plane variant at 697MB HBM FETCH and it LOST).
__global__ __launch_bounds__(256) void prep_p(const float* __restrict__ x,
                                              unsigned short* __restrict__ P) {
    int t = blockIdx.x * 256 + threadIdx.x;
    float4 a = reinterpret_cast<const float4*>(x)[t * 2];
    float4 b = reinterpret_cast<const float4*>(x)[t * 2 + 1];
    float r[8] = {a.x, a.y, a.z, a.w, b.x, b.y, b.z, b.w};
    u16x8 o;
#pragma unroll
    for (int j = 0; j < 8; ++j) {
        float xc = fminf(fmaxf(r[j], -9.0f), 9.0f);
        float e  = __expf(2.0f * xc);
        float th = (e - 1.0f) / (e + 1.0f);
        o[j] = (unsigned short)__float2uint_rn((th + 1.0f) * 32767.0f);
    }
    *reinterpret_cast<u16x8*>(&P[(size_t)t * 8]) = o;
}

// ---------- prep 2: split W[o][i][g] -> Wh/Wl bf16 planes [o][g*1024+i] ----------
__global__ __launch_bounds__(256) void prep_w(const float* __restrict__ W,
                                              unsigned short* __restrict__ Wh,
                                              unsigned short* __restrict__ Wl) {
    int t  = blockIdx.x * 256 + threadIdx.x;
    int o  = t >> 8, i4 = (t & 255) * 4;
    const float4* wp = reinterpret_cast<const float4*>(W + (size_t)o * KTOT + i4 * NG);
    float f[20];
#pragma unroll
    for (int q = 0; q < 5; ++q) {
        float4 v = wp[q];
        f[q*4+0] = v.x; f[q*4+1] = v.y; f[q*4+2] = v.z; f[q*4+3] = v.w;
    }
#pragma unroll
    for (int g = 0; g < NG; ++g) {
        ushort4 hq, lq;
        unsigned short* hp = (unsigned short*)&hq;
        unsigned short* lp = (unsigned short*)&lq;
#pragma unroll
        for (int di = 0; di < 4; ++di) {
            float w = f[di * NG + g];
            unsigned short h = f2bf_rne(w);
            hp[di] = h;
            lp[di] = f2bf_rne(w - bf2f(h));
        }
        int dst = o * KTOT + g * 1024 + i4;
        *reinterpret_cast<ushort4*>(&Wh[dst]) = hq;
        *reinterpret_cast<ushort4*>(&Wl[dst]) = lq;
    }
}

// ---------- main GEMM (mid structure + cross-step prefetch) ----------
// BM=64 x BN=256 x BK=32; 4 waves; transform redundancy 4 (vs R3's 8).
// LDS chunk-major [chunk][row][8]: frag reads are 256B-contiguous per
// 16-lane phase -> conflict-free (R3-class pattern measured 0 conflicts).
// KEY R6 LESSON: loads issued BEFORE a barrier are drained AT it (compiler
// emits s_waitcnt vmcnt(0) pre-s_barrier). So the kt+1 prefetch is issued
// AFTER the post-staging barrier -> flies under the whole MFMA phase and
// drains at the NEXT loop-top barrier, fully covered (~1900 cyc > HBM lat).
#define MBM 64
#define MBN 256
#define MBK 32
#define MNKT (KTOT / MBK)   // 160; kt -> g = kt>>5, i0 = (kt&31)*32

struct SLdsM {
    unsigned short Ah[4 * MBM * 8];   // [chunk][row][8]
    unsigned short Al[4 * MBM * 8];
    unsigned short Bh[4 * MBN * 8];
    unsigned short Bl[4 * MBN * 8];
};                                    // 40960 B

__global__ __launch_bounds__(256, 2) void kan_gemm_mid(
        const unsigned short* __restrict__ P,
        const unsigned short* __restrict__ Wh,
        const unsigned short* __restrict__ Wl,
        float* __restrict__ out) {
    __shared__ SLdsM s;

    // XCD mapping: 512 = 8 XCD x 64; XCD pair {2x,2x+1} shares o-panel x
    // (5.2 MB: mostly L2, L3-backed); mb contiguous within an XCD.
    int bid = blockIdx.x;
    int wg  = (bid & 7) * 64 + (bid >> 3);
    int nb  = wg >> 7, mb = wg & 127;
    int n0 = mb * MBM, o0 = nb * MBN;

    int tid  = threadIdx.x;
    int lane = tid & 63, w = tid >> 6;  // wave w -> cols [w*64, w*64+64)

    // A staging: thread -> (arow = tid>>2, aks = tid&3); 4-lane groups read
    // 64B contiguous of P (coalesced); LDS write chunk-major.
    int arow = tid >> 2, aks = tid & 3;
    int agoff = (n0 + arow) * IN_F + aks * 8;          // + i0 per kt
    int aldst = aks * (MBM * 8) + arow * 8;
    // B staging: thread -> (brow4 = tid>>2 within quarter q, bchunk = tid&3)
    int brow4 = tid >> 2, bchunk = tid & 3;
    int bldst = bchunk * (MBN * 8) + brow4 * 8;        // + q*512
    int bgq[4];
#pragma unroll
    for (int q = 0; q < 4; ++q)
        bgq[q] = (o0 + q * 64 + brow4) * KTOT + bchunk * 8;   // + k0 per kt
    // frag reads: verified convention (R3/R6 green): row = lane&15,
    // k-chunk = lane>>4; chunk-major -> contiguous bursts.
    int fchunk = lane >> 4, fr = lane & 15;

    f32x4 acc[4][4] = {};

    // ---- prologue: registers for kt = 0 ----
    u16x8 bregh[4], bregl[4], uP;
#pragma unroll
    for (int q = 0; q < 4; ++q) bregh[q] = *reinterpret_cast<const u16x8*>(&Wh[bgq[q]]);
#pragma unroll
    for (int q = 0; q < 4; ++q) bregl[q] = *reinterpret_cast<const u16x8*>(&Wl[bgq[q]]);
    uP = *reinterpret_cast<const u16x8*>(&P[agoff]);

    for (int kt = 0; kt < MNKT; ++kt) {
        float gv = -1.0f + 0.5f * (float)(kt >> 5);

        __syncthreads();   // (a) prev frag reads done; drains prefetch(kt)

        // ---- stage A(kt): hat-basis c = max(0, 1-2|xc-gv|), trunc-hi/lo ----
        {
            u16x8 hv, lv;
#pragma unroll
            for (int j = 0; j < 8; ++j) {
                float xc = fmaf((float)uP[j], (1.0f / 32767.0f), -1.0f);
                float c  = fmaxf(0.0f, fmaf(-2.0f, fabsf(xc - gv), 1.0f));
                unsigned hb = __float_as_uint(c) >> 16;         // trunc (c>=0)
                hv[j] = (unsigned short)hb;
                lv[j] = (unsigned short)(__float_as_uint(c - __uint_as_float(hb << 16)) >> 16);
            }
            *reinterpret_cast<u16x8*>(&s.Ah[aldst]) = hv;
            *reinterpret_cast<u16x8*>(&s.Al[aldst]) = lv;
        }
        // ---- stage B(kt) from prefetched regs ----
#pragma unroll
        for (int q = 0; q < 4; ++q) {
            *reinterpret_cast<u16x8*>(&s.Bh[bldst + q * 512]) = bregh[q];
            *reinterpret_cast<u16x8*>(&s.Bl[bldst + q * 512]) = bregl[q];
        }
        __syncthreads();   // (b) staging visible

        // ---- prefetch kt+1 (issued AFTER barrier -> hidden under MFMA) ----
        if (kt + 1 < MNKT) {
            int k0n = (kt + 1) * MBK;                  // == g*1024 + i0 (g-major)
            int i0n = ((kt + 1) & 31) * MBK;
#pragma unroll
            for (int q = 0; q < 4; ++q)
                bregh[q] = *reinterpret_cast<const u16x8*>(&Wh[bgq[q] + k0n]);
#pragma unroll
            for (int q = 0; q < 4; ++q)
                bregl[q] = *reinterpret_cast<const u16x8*>(&Wl[bgq[q] + k0n]);
            uP = *reinterpret_cast<const u16x8*>(&P[agoff + i0n]);
        }

        // ---- compute kt: frags + 48 MFMA (AhBh + AhBl + AlBh) ----
        s16x8 ah[4], al[4], bh[4], bl[4];
#pragma unroll
        for (int m = 0; m < 4; ++m) {
            int e = fchunk * (MBM * 8) + (m * 16 + fr) * 8;
            ah[m] = *reinterpret_cast<const s16x8*>(&s.Ah[e]);
            al[m] = *reinterpret_cast<const s16x8*>(&s.Al[e]);
        }
#pragma unroll
        for (int nf = 0; nf < 4; ++nf) {
            int e = fchunk * (MBN * 8) + (w * 64 + nf * 16 + fr) * 8;
            bh[nf] = *reinterpret_cast<const s16x8*>(&s.Bh[e]);
            bl[nf] = *reinterpret_cast<const s16x8*>(&s.Bl[e]);
        }
#pragma unroll
        for (int m = 0; m < 4; ++m)
#pragma unroll
            for (int nf = 0; nf < 4; ++nf) {
                acc[m][nf] = __builtin_amdgcn_mfma_f32_16x16x32_bf16(
                                 ah[m], bh[nf], acc[m][nf], 0, 0, 0);
                acc[m][nf] = __builtin_amdgcn_mfma_f32_16x16x32_bf16(
                                 ah[m], bl[nf], acc[m][nf], 0, 0, 0);
                acc[m][nf] = __builtin_amdgcn_mfma_f32_16x16x32_bf16(
                                 al[m], bh[nf], acc[m][nf], 0, 0, 0);
            }
    }

    // ---- epilogue: C/D col=lane&15, row=(lane>>4)*4+reg (R3/R6 green) ----
    int rb = n0 + (lane >> 4) * 4;
    int cb = o0 + w * 64 + (lane & 15);
#pragma unroll
    for (int m = 0; m < 4; ++m)
#pragma unroll
        for (int nf = 0; nf < 4; ++nf)
#pragma unroll
            for (int jj = 0; jj < 4; ++jj)
                out[(size_t)(rb + m * 16 + jj) * OUT_F + cb + nf * 16] =
                    acc[m][nf][jj];
}

// ---------- naive fallback (ws too small): correct, slow ----------
__global__ __launch_bounds__(256) void kan_naive(const float* __restrict__ x,
                                                 const float* __restrict__ W,
                                                 float* __restrict__ out) {
    int bn = blockIdx.x & 3;
    int bm = blockIdx.x >> 2;
    int o = bn * 256 + threadIdx.x;
    int nbase = bm * 16;
    float acc[16];
#pragma unroll
    for (int j = 0; j < 16; ++j) acc[j] = 0.0f;
    for (int i = 0; i < IN_F; ++i) {
        const float* wp = &W[(size_t)o * KTOT + i * NG];
        float w0 = wp[0], w1 = wp[1], w2 = wp[2], w3 = wp[3], w4 = wp[4];
#pragma unroll
        for (int j = 0; j < 16; ++j) {
            float xc = tanhf(x[(size_t)(nbase + j) * IN_F + i]);
            float c0 = fmaxf(0.f, fmaf(-2.f, fabsf(xc + 1.0f), 1.f));
            float c1 = fmaxf(0.f, fmaf(-2.f, fabsf(xc + 0.5f), 1.f));
            float c2 = fmaxf(0.f, fmaf(-2.f, fabsf(xc), 1.f));
            float c3 = fmaxf(0.f, fmaf(-2.f, fabsf(xc - 0.5f), 1.f));
            float c4 = fmaxf(0.f, fmaf(-2.f, fabsf(xc - 1.0f), 1.f));
            acc[j] += c0 * w0 + c1 * w1 + c2 * w2 + c3 * w3 + c4 * w4;
        }
    }
#pragma unroll
    for (int j = 0; j < 16; ++j)
        out[(size_t)(nbase + j) * OUT_F + o] = acc[j];
}

extern "C" void kernel_launch(void* const* d_in, const int* in_sizes, int n_in,
                              void* d_out, int out_size, void* d_ws, size_t ws_size,
                              hipStream_t stream) {
    const float* x = (const float*)d_in[0];
    const float* W = (const float*)d_in[1];
    float* out = (float*)d_out;

    const size_t P_BYTES = (size_t)N_ROWS * IN_F * 2;      // 16 MiB
    const size_t WPLANE  = (size_t)OUT_F * KTOT * 2;       // 10 MiB each

    if (ws_size >= P_BYTES + 2 * WPLANE) {
        unsigned short* P  = (unsigned short*)d_ws;
        unsigned short* Wh = (unsigned short*)((char*)d_ws + P_BYTES);
        unsigned short* Wl = (unsigned short*)((char*)d_ws + P_BYTES + WPLANE);
        prep_p<<<(N_ROWS * IN_F / 8) / 256, 256, 0, stream>>>(x, P);
        prep_w<<<(OUT_F * IN_F / 4) / 256, 256, 0, stream>>>(W, Wh, Wl);
        kan_gemm_mid<<<512, 256, 0, stream>>>(P, Wh, Wl, out);
    } else {
        kan_naive<<<2048, 256, 0, stream>>>(x, W, out);
    }
}

// Round 9
// 325.326 us; speedup vs baseline: 1.2607x; 1.2607x over previous
//
#include <hip/hip_runtime.h>
#include <stdint.h>

#define N_ROWS 8192
#define IN_F   1024
#define OUT_F  1024
#define NG     5
#define KTOT   (IN_F * NG)  // 5120, k = g*1024 + i (g-major)

typedef float          f32x4 __attribute__((ext_vector_type(4)));
typedef short          s16x8 __attribute__((ext_vector_type(8)));
typedef unsigned short u16x8 __attribute__((ext_vector_type(8)));

__device__ __forceinline__ unsigned short f2bf_rne(float f) {
    unsigned u = __float_as_uint(f);
    u = (u + 0x7fffu + ((u >> 16) & 1u)) >> 16;
    return (unsigned short)u;
}
__device__ __forceinline__ float bf2f(unsigned short h) {
    return __uint_as_float(((unsigned)h) << 16);
}
__device__ __forceinline__ void gload_lds16(const void* g, void* l) {
    __builtin_amdgcn_global_load_lds(
        (const __attribute__((address_space(1))) unsigned int*)g,
        (__attribute__((address_space(3))) unsigned int*)l, 16, 0, 0);
}

// ---------- prep 1 (FROZEN, green R3/R7): P[n][i] = u16(tanh(x)) ----------
__global__ __launch_bounds__(256) void prep_p(const float* __restrict__ x,
                                              unsigned short* __restrict__ P) {
    int t = blockIdx.x * 256 + threadIdx.x;
    float4 a = reinterpret_cast<const float4*>(x)[t * 2];
    float4 b = reinterpret_cast<const float4*>(x)[t * 2 + 1];
    float r[8] = {a.x, a.y, a.z, a.w, b.x, b.y, b.z, b.w};
    u16x8 o;
#pragma unroll
    for (int j = 0; j < 8; ++j) {
        float xc = fminf(fmaxf(r[j], -9.0f), 9.0f);
        float e  = __expf(2.0f * xc);
        float th = (e - 1.0f) / (e + 1.0f);
        o[j] = (unsigned short)__float2uint_rn((th + 1.0f) * 32767.0f);
    }
    *reinterpret_cast<u16x8*>(&P[(size_t)t * 8]) = o;
}

// ---------- prep 2 (FROZEN, green): W -> Wh/Wl bf16 planes [o][g*1024+i] ----------
__global__ __launch_bounds__(256) void prep_w(const float* __restrict__ W,
                                              unsigned short* __restrict__ Wh,
                                              unsigned short* __restrict__ Wl) {
    int t  = blockIdx.x * 256 + threadIdx.x;
    int o  = t >> 8, i4 = (t & 255) * 4;
    const float4* wp = reinterpret_cast<const float4*>(W + (size_t)o * KTOT + i4 * NG);
    float f[20];
#pragma unroll
    for (int q = 0; q < 5; ++q) {
        float4 v = wp[q];
        f[q*4+0] = v.x; f[q*4+1] = v.y; f[q*4+2] = v.z; f[q*4+3] = v.w;
    }
#pragma unroll
    for (int g = 0; g < NG; ++g) {
        ushort4 hq, lq;
        unsigned short* hp = (unsigned short*)&hq;
        unsigned short* lp = (unsigned short*)&lq;
#pragma unroll
        for (int di = 0; di < 4; ++di) {
            float w = f[di * NG + g];
            unsigned short h = f2bf_rne(w);
            hp[di] = h;
            lp[di] = f2bf_rne(w - bf2f(h));
        }
        int dst = o * KTOT + g * 1024 + i4;
        *reinterpret_cast<ushort4*>(&Wh[dst]) = hq;
        *reinterpret_cast<ushort4*>(&Wl[dst]) = lq;
    }
}

// ---------- main GEMM: BM=64 x BN=256 x BK=32, 2-product (Ah*Bh + Ah*Bl) ----
// LDS per-row layout (XOR swizzle, 0 conflicts measured in R6's BK=32 form):
//   elem[row*32 + (ks ^ ((row>>1)&3))*8 + j] = T[row][ks*8 + j]
// Frag-read bank audit: 16 lanes, rows r..r+15 at one k-chunk: even rows ->
// banks 0..15 across 4 XOR'd slot groups, odd rows -> 16..31; 2-way = free.
#define BM 64
#define BN 256
#define BK 32
#define NKT (KTOT / BK)     // 160; g = kt>>5, i0 = (kt&31)*32

struct SLds {
    unsigned short Ah[BM * BK];     //  4 KB (single A plane: 2-product)
    unsigned short Bh[BN * BK];     // 16 KB
    unsigned short Bl[BN * BK];     // 16 KB
};                                  // 36 KB -> 2 blocks/CU (grid-limited)

__global__ __launch_bounds__(256, 2) void kan_gemm(
        const unsigned short* __restrict__ P,
        const unsigned short* __restrict__ Wh,
        const unsigned short* __restrict__ Wl,
        float* __restrict__ out) {
    __shared__ SLds s;

    // XCD swizzle (R7 mapping, green): 512 = 8 XCD x 64 contiguous
    int bid = blockIdx.x;
    int wg  = (bid & 7) * 64 + (bid >> 3);
    int nb  = wg >> 7, mb = wg & 127;
    int n0 = mb * BM, o0 = nb * BN;

    int tid  = threadIdx.x;
    int lane = tid & 63, wid = tid >> 6;   // wave wid -> cols [wid*64, +64)

    // ---- A staging map: thread -> (row = tid>>2, ks = tid&3), one u16x8 ----
    int arow = tid >> 2, aks = tid & 3;
    int agoff = (n0 + arow) * IN_F + aks * 8;              // + i0 per kt
    int adst  = arow * BK + ((aks ^ ((arow >> 1) & 3)) << 3);
    // ---- B staging (gload_lds, per-lane pre-swizzled global src; m173) ----
    // gload q covers rows wid*64+q*16 .. +16; lane l -> row_off l>>2, slot l&3;
    // global ks = (l&3) ^ ((l>>3)&3)   [= slot ^ ((row>>1)&3); wid*64, q*16
    // contribute multiples of 8 to row so (row>>1)&3 == (l>>3)&3]
    int bks = (lane & 3) ^ ((lane >> 3) & 3);
    int boffq[4], bldsq[4];
#pragma unroll
    for (int q = 0; q < 4; ++q) {
        int row = wid * 64 + q * 16 + (lane >> 2);
        boffq[q] = (o0 + row) * KTOT + bks * 8;            // + k0 per kt
        bldsq[q] = (wid * 64 + q * 16) * BK;               // wave-uniform base
    }
    // ---- frag-read bases (loop-invariant; (row>>1)&3 == (fr>>1)&3 for all
    //      m/nf since m*16, nf*16, wid*64 are multiples of 8) ----
    int fr = lane & 15, sl0 = lane >> 4;
    int aswz  = sl0 ^ ((fr >> 1) & 3);
    int abase = fr * BK + aswz * 8;                        // + m*512 elems
    int bbase = (wid * 64 + fr) * BK + aswz * 8;           // + nf*512 elems

    f32x4 acc[4][4] = {};

    // T14 P-prefetch (green R3): registers for kt staged during kt-1
    u16x8 ucur = *reinterpret_cast<const u16x8*>(&P[agoff]);

    for (int kt = 0; kt < NKT; ++kt) {
        int k0 = kt * BK;
        // A-transform constant (R8 audit fix): d = xc - gv
        //   = (u/32767 - 1) - (-1 + 0.5g) = fma(u, 1/32767, -0.5g)
        float c1 = -0.5f * (float)(kt >> 5);

        __syncthreads();   // barrier-1: prev frag reads done; prev prefetch drained

        // ---- B: issue async gl_lds first; drains at barrier-2 under VALU ----
#pragma unroll
        for (int q = 0; q < 4; ++q) {
            gload_lds16(Wh + boffq[q] + k0, &s.Bh[bldsq[q]]);
            gload_lds16(Wl + boffq[q] + k0, &s.Bl[bldsq[q]]);
        }
        // ---- P prefetch for kt+1 ----
        int ktn = (kt + 1 < NKT) ? kt + 1 : 0;
        u16x8 unext = *reinterpret_cast<const u16x8*>(&P[agoff + (ktn & 31) * BK]);

        // ---- A transform: c = max(0, 1-2|xc-gv|), RNE -> single bf16 ----
        {
            u16x8 hv;
#pragma unroll
            for (int j = 0; j < 8; ++j) {
                float d = fmaf((float)ucur[j], (1.0f / 32767.0f), c1); // xc-gv
                float c = fmaxf(0.0f, fmaf(-2.0f, fabsf(d), 1.0f));
                hv[j] = f2bf_rne(c);
            }
            *reinterpret_cast<u16x8*>(&s.Ah[adst]) = hv;
        }
        ucur = unext;

        __syncthreads();   // barrier-2: vmcnt(0) drain -> B landed; A visible

        // ---- compute: 12 frag reads + 32 MFMA (AhBh + AhBl) ----
        s16x8 ah[4], bh[4], bl[4];
#pragma unroll
        for (int m = 0; m < 4; ++m)
            ah[m] = *reinterpret_cast<const s16x8*>(&s.Ah[abase + m * 512]);
#pragma unroll
        for (int nf = 0; nf < 4; ++nf) {
            bh[nf] = *reinterpret_cast<const s16x8*>(&s.Bh[bbase + nf * 512]);
            bl[nf] = *reinterpret_cast<const s16x8*>(&s.Bl[bbase + nf * 512]);
        }
#pragma unroll
        for (int m = 0; m < 4; ++m)
#pragma unroll
            for (int nf = 0; nf < 4; ++nf) {
                acc[m][nf] = __builtin_amdgcn_mfma_f32_16x16x32_bf16(
                                 ah[m], bh[nf], acc[m][nf], 0, 0, 0);
                acc[m][nf] = __builtin_amdgcn_mfma_f32_16x16x32_bf16(
                                 ah[m], bl[nf], acc[m][nf], 0, 0, 0);
            }
    }

    // ---- epilogue: C/D col=lane&15, row=(lane>>4)*4+reg (green R3/R6/R7) ----
    int rb = n0 + (lane >> 4) * 4;
    int cb = o0 + wid * 64 + (lane & 15);
#pragma unroll
    for (int m = 0; m < 4; ++m)
#pragma unroll
        for (int nf = 0; nf < 4; ++nf)
#pragma unroll
            for (int jj = 0; jj < 4; ++jj)
                out[(size_t)(rb + m * 16 + jj) * OUT_F + cb + nf * 16] =
                    acc[m][nf][jj];
}

// ---------- naive fallback (ws too small): correct, slow ----------
__global__ __launch_bounds__(256) void kan_naive(const float* __restrict__ x,
                                                 const float* __restrict__ W,
                                                 float* __restrict__ out) {
    int bn = blockIdx.x & 3;
    int bm = blockIdx.x >> 2;
    int o = bn * 256 + threadIdx.x;
    int nbase = bm * 16;
    float acc[16];
#pragma unroll
    for (int j = 0; j < 16; ++j) acc[j] = 0.0f;
    for (int i = 0; i < IN_F; ++i) {
        const float* wp = &W[(size_t)o * KTOT + i * NG];
        float w0 = wp[0], w1 = wp[1], w2 = wp[2], w3 = wp[3], w4 = wp[4];
#pragma unroll
        for (int j = 0; j < 16; ++j) {
            float xc = tanhf(x[(size_t)(nbase + j) * IN_F + i]);
            float c0 = fmaxf(0.f, fmaf(-2.f, fabsf(xc + 1.0f), 1.f));
            float c1 = fmaxf(0.f, fmaf(-2.f, fabsf(xc + 0.5f), 1.f));
            float c2 = fmaxf(0.f, fmaf(-2.f, fabsf(xc), 1.f));
            float c3 = fmaxf(0.f, fmaf(-2.f, fabsf(xc - 0.5f), 1.f));
            float c4 = fmaxf(0.f, fmaf(-2.f, fabsf(xc - 1.0f), 1.f));
            acc[j] += c0 * w0 + c1 * w1 + c2 * w2 + c3 * w3 + c4 * w4;
        }
    }
#pragma unroll
    for (int j = 0; j < 16; ++j)
        out[(size_t)(nbase + j) * OUT_F + o] = acc[j];
}

extern "C" void kernel_launch(void* const* d_in, const int* in_sizes, int n_in,
                              void* d_out, int out_size, void* d_ws, size_t ws_size,
                              hipStream_t stream) {
    const float* x = (const float*)d_in[0];
    const float* W = (const float*)d_in[1];
    float* out = (float*)d_out;

    const size_t P_BYTES = (size_t)N_ROWS * IN_F * 2;      // 16 MiB
    const size_t WPLANE  = (size_t)OUT_F * KTOT * 2;       // 10 MiB each

    if (ws_size >= P_BYTES + 2 * WPLANE) {
        unsigned short* P  = (unsigned short*)d_ws;
        unsigned short* Wh = (unsigned short*)((char*)d_ws + P_BYTES);
        unsigned short* Wl = (unsigned short*)((char*)d_ws + P_BYTES + WPLANE);
        prep_p<<<(N_ROWS * IN_F / 8) / 256, 256, 0, stream>>>(x, P);
        prep_w<<<(OUT_F * IN_F / 4) / 256, 256, 0, stream>>>(W, Wh, Wl);
        kan_gemm<<<512, 256, 0, stream>>>(P, Wh, Wl, out);
    } else {
        kan_naive<<<2048, 256, 0, stream>>>(x, W, out);
    }
}